// Round 3
// baseline (1568.132 us; speedup 1.0000x reference)
//
#include <hip/hip_runtime.h>
#include <math.h>

#define BATCH 16
#define EMB   32
#define HW    262144          // 512*512
#define NL    3

#define TILE_PX        256
#define TILES_PER_IMG  (HW / TILE_PX)     // 1024

// ---- workspace layout (floats) ----
#define WS_COUNTS 0                     // BATCH*4
#define WS_SE     64                    // BATCH*96  sum_emb[b][l][e]
#define WS_SH     (WS_SE + BATCH*96)    // BATCH*96  sum_hat[b][l][e]
#define WS_CE     (WS_SH + BATCH*96)    // 1
#define WS_FLOATS (WS_CE + 1)

__device__ __forceinline__ float ce1(float a, float b, float c, int l) {
    const float m = fmaxf(fmaxf(a, b), c);
    const float s = __expf(a - m) + __expf(b - m) + __expf(c - m);
    const float zl = (l == 0) ? a : ((l == 1) ? b : c);
    return m + __logf(s) - zl;
}

// ============================================================================
// LDS-staged fused kernel. One 256-px tile per block.
//  Phase S (stage):   wave w owns channels w*8..w*8+7. Lane loads float4
//                     (16B) per channel -> 1KB contiguous per wave instr
//                     (perfectly coalesced HBM). Squares on the fly into a
//                     per-lane float4 partial; raw values ds_write'd into
//                     embT[32][257] (padded rows -> bank-friendly reads).
//  Phase N (norm+CE): thread t owns pixel t. invn = rsqrt of the 4 staged
//                     partials; CE from coalesced pred loads.
//  Phase B (accum):   channel-split: thread (cg,pl) owns channels cg*4..+3,
//                     pixels pl+32s. All reads from LDS (b32, 2-way = free).
// HBM touched exactly once, always contiguous. No shuffles in hot loops.
// ============================================================================
__global__ __launch_bounds__(256) void fused_kernel(
        const float* __restrict__ emb, const float* __restrict__ pred,
        const int* __restrict__ label, float* __restrict__ ws)
{
    const int tid = threadIdx.x;
    const int wv  = tid >> 6;          // wave 0..3
    const int l   = tid & 63;          // lane
    const int b   = blockIdx.x >> 10;              // /TILES_PER_IMG
    const int t0  = (blockIdx.x & 1023) * TILE_PX; // tile pixel base

    const float* embB  = emb   + (size_t)b * EMB * HW + t0;
    const float* predB = pred  + (size_t)b * 3 * HW + t0;
    const int*   labB  = label + (size_t)b * HW + t0;

    __shared__ float embT[32][TILE_PX + 1];   // padded: bank = (c + px) % 32
    __shared__ float partF[4][TILE_PX];       // per-wave ssq partials
    __shared__ float invnL[TILE_PX];
    __shared__ int   labL[TILE_PX];

    // ---------------- Phase S: coalesced stage + on-the-fly squares --------
    float4 ps4 = {0.f, 0.f, 0.f, 0.f};
    #pragma unroll
    for (int i = 0; i < 8; ++i) {
        const int c = wv * 8 + i;
        const float4 v = *(const float4*)(embB + (size_t)c * HW + l * 4);
        ps4.x = fmaf(v.x, v.x, ps4.x);
        ps4.y = fmaf(v.y, v.y, ps4.y);
        ps4.z = fmaf(v.z, v.z, ps4.z);
        ps4.w = fmaf(v.w, v.w, ps4.w);
        *(float4*)&embT[c][l * 4] = v;
    }
    *(float4*)&partF[wv][l * 4] = ps4;
    if (wv == 0) {   // stage labels: 64 lanes x int4 = 256 labels
        const int4 lb4 = *(const int4*)(labB + l * 4);
        *(int4*)&labL[l * 4] = lb4;
    }
    __syncthreads();

    // ---------------- Phase N: per-pixel invnorm + CE ----------------------
    const float ss = partF[0][tid] + partF[1][tid] + partF[2][tid] + partF[3][tid];
    const float iv = 1.0f / fmaxf(sqrtf(ss), 1e-8f);
    invnL[tid] = iv;
    const int lbp = labL[tid];
    const float z0 = predB[tid];
    const float z1 = predB[HW + tid];
    const float z2 = predB[2 * HW + tid];
    float ce = ce1(z0, z1, z2, lbp);
    __syncthreads();

    // ---------------- Phase B: channel-split accumulation from LDS ---------
    const int cg = tid >> 5;       // channel group 0..7 (channels cg*4..+3)
    const int pl = tid & 31;       // pixel-slot within stride-32 sweep
    const int c0 = cg * 4;

    float accE[NL][4] = {};
    float accH[2][4]  = {};
    float cnt0 = 0.f, cnt1 = 0.f, cnt2 = 0.f;

    #pragma unroll
    for (int s = 0; s < 8; ++s) {
        const int p = pl + 32 * s;
        const int lb = labL[p];
        const float ivp = invnL[p];
        const float m0 = (lb == 0) ? 1.f : 0.f;
        const float m1 = (lb == 1) ? 1.f : 0.f;
        const float m2 = (lb == 2) ? 1.f : 0.f;
        if (cg == 0) { cnt0 += m0; cnt1 += m1; cnt2 += m2; }
        #pragma unroll
        for (int k = 0; k < 4; ++k) {
            const float v  = embT[c0 + k][p];
            const float vh = v * ivp;
            accE[0][k] = fmaf(m0, v,  accE[0][k]);
            accE[1][k] = fmaf(m1, v,  accE[1][k]);
            accE[2][k] = fmaf(m2, v,  accE[2][k]);
            accH[0][k] = fmaf(m1, vh, accH[0][k]);
            accH[1][k] = fmaf(m2, vh, accH[1][k]);
        }
    }

    // ---- reduce over the 32 pixel-slots (lanes sharing a cg half-wave) ----
    #pragma unroll
    for (int o = 16; o >= 1; o >>= 1) {
        #pragma unroll
        for (int ll = 0; ll < NL; ++ll)
            #pragma unroll
            for (int k = 0; k < 4; ++k)
                accE[ll][k] += __shfl_xor(accE[ll][k], o);
        #pragma unroll
        for (int ll = 0; ll < 2; ++ll)
            #pragma unroll
            for (int k = 0; k < 4; ++k)
                accH[ll][k] += __shfl_xor(accH[ll][k], o);
        cnt0 += __shfl_xor(cnt0, o);
        cnt1 += __shfl_xor(cnt1, o);
        cnt2 += __shfl_xor(cnt2, o);
    }
    // CE: one pixel per thread -> full-wave butterfly, one atomic per wave
    #pragma unroll
    for (int o = 32; o >= 1; o >>= 1) ce += __shfl_xor(ce, o);

    if (pl == 0) {
        float* se = ws + WS_SE + b * 96;
        float* sh = ws + WS_SH + b * 96;
        #pragma unroll
        for (int ll = 0; ll < NL; ++ll)
            #pragma unroll
            for (int k = 0; k < 4; ++k)
                atomicAdd(&se[ll*32 + c0 + k], accE[ll][k]);
        #pragma unroll
        for (int ll = 0; ll < 2; ++ll)
            #pragma unroll
            for (int k = 0; k < 4; ++k)
                atomicAdd(&sh[(ll+1)*32 + c0 + k], accH[ll][k]);
    }
    if (l == 0) atomicAdd(&ws[WS_CE], ce * (1.0f / (float)HW));
    if (tid == 0) {
        atomicAdd(&ws[WS_COUNTS + b*4 + 0], cnt0);
        atomicAdd(&ws[WS_COUNTS + b*4 + 1], cnt1);
        atomicAdd(&ws[WS_COUNTS + b*4 + 2], cnt2);
    }
}

// ============================================================================
// Finalize. Block 512 = 16 images x 32 channels.
// ============================================================================
__global__ __launch_bounds__(512) void final_kernel(
        const int* __restrict__ nbr, const float* __restrict__ ws,
        float* __restrict__ out)
{
    const int tid = threadIdx.x;
    const int b = tid >> 5;
    const int e = tid & 31;
    __shared__ float total;
    if (tid == 0) total = 0.f;
    __syncthreads();

    const float* se = ws + WS_SE + b * 96;
    const float* sh = ws + WS_SH + b * 96;
    const float c0 = ws[WS_COUNTS + b*4 + 0];
    const float c1 = ws[WS_COUNTS + b*4 + 1];
    const float c2 = ws[WS_COUNTS + b*4 + 2];

    float mean0 = se[0*32 + e] / c0;
    float mean1 = se[1*32 + e] / c1;
    float mean2 = se[2*32 + e] / c2;

    float n0 = mean0*mean0, n1 = mean1*mean1, n2 = mean2*mean2;
    #pragma unroll
    for (int o = 16; o >= 1; o >>= 1) {
        n0 += __shfl_xor(n0, o);
        n1 += __shfl_xor(n1, o);
        n2 += __shfl_xor(n2, o);
    }
    const float nm0 = mean0 / fmaxf(sqrtf(n0), 1e-12f);
    const float nm1 = mean1 / fmaxf(sqrtf(n1), 1e-12f);
    const float nm2 = mean2 / fmaxf(sqrtf(n2), 1e-12f);

    float d1  = nm1 * sh[1*32 + e];
    float d2  = nm2 * sh[2*32 + e];
    float s10 = nm1 * nm0, s11 = nm1 * nm1, s12 = nm1 * nm2;
    float s20 = nm2 * nm0, s21 = nm2 * nm1, s22 = nm2 * nm2;
    #pragma unroll
    for (int o = 16; o >= 1; o >>= 1) {
        d1  += __shfl_xor(d1, o);  d2  += __shfl_xor(d2, o);
        s10 += __shfl_xor(s10, o); s11 += __shfl_xor(s11, o); s12 += __shfl_xor(s12, o);
        s20 += __shfl_xor(s20, o); s21 += __shfl_xor(s21, o); s22 += __shfl_xor(s22, o);
    }

    if (e == 0) {
        float S[3][3];
        S[1][0] = s10; S[1][1] = s11; S[1][2] = s12;
        S[2][0] = s20; S[2][1] = s21; S[2][2] = s22;
        S[0][0] = S[0][1] = S[0][2] = 0.f;
        float mask[3][3] = {{0.f,0.f,0.f},{0.f,0.f,0.f},{0.f,0.f,0.f}};
        for (int row = 1; row < 3; ++row) {
            int prod = 1;
            for (int j = 0; j < 3; ++j) {
                const int v = nbr[b*9 + row*3 + j];
                if (v == 0) prod = 0;           // cumprod includes current elem
                if (prod) mask[row][v] = 1.f;   // scatter-max
            }
        }
        float num = 0.f, den = 0.f;
        for (int row = 1; row < 3; ++row)
            for (int col = 0; col < 3; ++col) {
                num += S[row][col] * mask[row][col];
                den += mask[row][col];
            }
        const float inter = num / den;
        const float ip1 = 1.f - d1 / c1;
        const float ip2 = 1.f - d2 / c2;
        const float loss = 0.5f * (ip1 + ip2) + inter;
        atomicAdd(&total, loss);
    }
    __syncthreads();
    if (tid == 0) out[0] = total + ws[WS_CE];
}

// ============================================================================
extern "C" void kernel_launch(void* const* d_in, const int* in_sizes, int n_in,
                              void* d_out, int out_size, void* d_ws, size_t ws_size,
                              hipStream_t stream) {
    const float* emb   = (const float*)d_in[0];
    const float* pred  = (const float*)d_in[1];
    const int*   label = (const int*)d_in[2];
    const int*   nbr   = (const int*)d_in[3];
    float* ws  = (float*)d_ws;
    float* out = (float*)d_out;

    hipMemsetAsync(d_ws, 0, WS_FLOATS * sizeof(float), stream);
    fused_kernel<<<BATCH * TILES_PER_IMG, 256, 0, stream>>>(emb, pred, label, ws);
    final_kernel<<<1, 512, 0, stream>>>(nbr, ws, out);
}